// Round 8
// baseline (103.220 us; speedup 1.0000x reference)
//
#include <hip/hip_runtime.h>
#include <hip/hip_bf16.h>

// Problem constants (B,C,H,W)=(8,256,32,32), heads=8, head_dim=32
#define BB 8
#define CC 256
#define NPIX 1024          // H*W
#define NH 8
#define HD 32
#define QKVO 768           // 3*256
#define EPS 1e-5f

typedef __attribute__((ext_vector_type(4)))  float floatx4;
typedef __attribute__((ext_vector_type(16))) float floatx16;
typedef __attribute__((ext_vector_type(8)))  short bf16x8;

// Q/K/V are stored in MFMA-fragment order:
//   frag buffer block for (bh, tile32) = 1024 bf16 = [sub(2)][lane(64)][elem(8)]
//   Q (B-op): lane = (n&31) + 32*((d>>3)&1), sub = d>>4,        elem = d&7
//   K (A-op): lane = (m&31) + 32*((d>>3)&1), sub = d>>4,        elem = d&7
//   V (A-op): lane = d      + 32*((m&15)>>3), sub = (m&31)>>4,  elem = m&7
// Q is pre-scaled by head_dim^-0.5 * log2(e) so softmax is p = 2^st.

// ---------------------------------------------------------------- f32 -> bf16 (both weights, one launch)
__global__ __launch_bounds__(256) void f2b_cvt2(const float* __restrict__ a, __hip_bfloat16* __restrict__ oa, int na,
                                                const float* __restrict__ b, __hip_bfloat16* __restrict__ ob, int nb) {
    int i = blockIdx.x * 256 + threadIdx.x;
    if (i < na) oa[i] = __float2bfloat16(a[i]);
    else if (i - na < nb) ob[i - na] = __float2bfloat16(b[i - na]);
}

// ---------------------------------------------------------------- fused LN + QKV GEMM -> fragment buffers
__global__ __launch_bounds__(512) void ln_qkv(const float* __restrict__ x,
                                              const float* __restrict__ gamma,
                                              const float* __restrict__ beta,
                                              const __hip_bfloat16* __restrict__ wq,
                                              const float* __restrict__ bq,
                                              __hip_bfloat16* __restrict__ qf,
                                              __hip_bfloat16* __restrict__ kf,
                                              __hip_bfloat16* __restrict__ vf) {
    __shared__ short xbn[32 * 256];      // 16 KB normalized tile, swizzled
    __shared__ float s_part[16][33];
    __shared__ float q_part[16][33];
    __shared__ float s_mu[32], s_rs[32];

    const int tid  = threadIdx.x;
    const int P0   = blockIdx.x * 32;    // global pixel base (32 | 1024: no batch straddle)
    const int b    = P0 >> 10;
    const int nloc = tid & 31;
    const int g    = tid >> 5;           // 0..15
    const float* xb = x + (size_t)b * CC * NPIX + (P0 & 1023);

    // ---- Phase A: stats; load exactly the 16 channels phase B will emit,
    //      keep them in registers (channels g*8..+7 and 128+g*8..+7)
    float vals[16];
    float s = 0.f, s2 = 0.f;
    #pragma unroll
    for (int j = 0; j < 8; ++j) {
        float v = xb[(size_t)(g * 8 + j) * NPIX + nloc];
        vals[j] = v; s += v; s2 += v * v;
    }
    #pragma unroll
    for (int j = 0; j < 8; ++j) {
        float v = xb[(size_t)(128 + g * 8 + j) * NPIX + nloc];
        vals[8 + j] = v; s += v; s2 += v * v;
    }
    s_part[g][nloc] = s; q_part[g][nloc] = s2;
    __syncthreads();
    if (tid < 32) {
        float ss = 0.f, qq = 0.f;
        #pragma unroll
        for (int k = 0; k < 16; ++k) { ss += s_part[k][tid]; qq += q_part[k][tid]; }
        float mu  = ss * (1.f / CC);
        float var = qq * (1.f / CC) - mu * mu;
        s_mu[tid] = mu; s_rs[tid] = rsqrtf(var + EPS);
    }
    __syncthreads();

    // ---- Phase B: normalize from registers -> swizzled LDS bf16
    {
        const float mu = s_mu[nloc], rs = s_rs[nloc];
        #pragma unroll
        for (int half = 0; half < 2; ++half) {
            int cb = g + half * 16;            // 8-channel block index
            union { bf16x8 v; unsigned short us[8]; } pk;
            #pragma unroll
            for (int j = 0; j < 8; ++j) {
                int c = cb * 8 + j;
                float v = vals[half * 8 + j];
                pk.us[j] = __bfloat16_as_ushort(__float2bfloat16((v - mu) * rs * gamma[c] + beta[c]));
            }
            int idx = (nloc * 256 + cb * 8) ^ ((nloc & 31) << 3);
            *(bf16x8*)(&xbn[idx]) = pk.v;
        }
    }
    __syncthreads();

    // ---- Phase C: GEMM 32 x 768 x 256
    const int w = tid >> 6, lane = tid & 63, lr = lane & 15, lg = lane >> 4;
    const int mstrip = (w & 1) * 16;        // two 16-row strips
    const int ob     = (w >> 1) * 192;      // four o-blocks of 192 (= 2 heads)
    floatx4 acc[12] = {};
    for (int kk = 0; kk < CC; kk += 32) {
        const int arow = mstrip + lr;
        const int aidx = (arow * 256 + kk + lg * 8) ^ ((arow & 31) << 3);
        bf16x8 a = *(const bf16x8*)(&xbn[aidx]);
        #pragma unroll
        for (int nt = 0; nt < 12; ++nt) {
            const int o = ob + nt * 16 + lr;
            bf16x8 bfr = *(const bf16x8*)(wq + (size_t)o * CC + kk + lg * 8);
            acc[nt] = __builtin_amdgcn_mfma_f32_16x16x32_bf16(a, bfr, acc[nt], 0, 0, 0);
        }
    }
    // ---- epilogue: write fragment-order Q/K/V.  Q is pre-scaled by
    //      head_dim^-0.5 * log2(e) so attention's softmax is p = 2^st.
    const float QSCALE = 0.25503495f;       // 0.17677669529663689 * 1.4426950408889634
    const int m_base = mstrip + lg * 4;     // m_in base (0..28, mult of 4)
    const int tile   = blockIdx.x & 31;     // pixel tile within image
    #pragma unroll
    for (int nt = 0; nt < 12; ++nt) {
        const int o = ob + nt * 16 + lr;
        const int h = o / 96, om = o % 96;  // uniform per nt across the 16-lane run
        const float bias = bq[o];
        const size_t fb = (size_t)((b * NH + h) * 32 + tile) * 1024;
        if (om < 64) {                      // Q or K: 4 scalar 2B stores (lane varies with m)
            const int d = om & 31;
            const bool isq = (om < 32);
            __hip_bfloat16* dst = (isq ? qf : kf);
            const float sc = isq ? QSCALE : 1.0f;
            const int off = (d >> 4) * 512 + ((d >> 3) & 1) * 256 + (d & 7);
            #pragma unroll
            for (int r = 0; r < 4; ++r)
                dst[fb + off + (m_base + r) * 8] = __float2bfloat16((acc[nt][r] + bias) * sc);
        } else {                            // V: 4 consecutive m -> one uint2 store
            const int d = om - 64;
            const int half = m_base >> 4, hi = (m_base >> 3) & 1, j0 = m_base & 7;
            union { unsigned short us[4]; uint2 u; } pv;
            #pragma unroll
            for (int r = 0; r < 4; ++r)
                pv.us[r] = __bfloat16_as_ushort(__float2bfloat16(acc[nt][r] + bias));
            *(uint2*)(vf + fb + half * 512 + (d + 32 * hi) * 8 + j0) = pv.u;
        }
    }
}

// ---------------------------------------------------------------- attention PROBE (x4 repeat, idempotent)
// Body = attn5 (reg double-buffer, raw v_exp_f32, cvt_pk+permlane) — the
// best-measured variant. Repeated REP times with laundered pointers so the
// compiler cannot CSE across reps; every rep writes identical obuf values.
// Purpose: dur ≈ 4x attn -> rises into rocprof top-5 WITH counters
// (VALUBusy / MfmaUtil / Occupancy / VGPR / LDS conflicts) for diagnosis.
#define REP 4
__global__ __launch_bounds__(512, 4) void attn_probe(const __hip_bfloat16* __restrict__ qf_in,
                                                     const __hip_bfloat16* __restrict__ kf_in,
                                                     const __hip_bfloat16* __restrict__ vf_in,
                                                     __hip_bfloat16* __restrict__ obuf) {
    __shared__ float m_lds[4][64][17];       // KV-half merge: 16 acc + lsum
    __shared__ float t_lds[4][32][33];       // output transpose, per-wave private

    const int flat = blockIdx.y * 64 + blockIdx.x;          // 0..511
    const int bh   = (flat & 7) * 8 + ((flat >> 3) & 7);    // XCD-bijective remap
    const int qg   = flat >> 6;                             // 0..7
    const int b = bh >> 3, h = bh & 7;
    const int tid = threadIdx.x, w = tid >> 6, lane = tid & 63;
    const int lc = lane & 31, hi = lane >> 5;
    const int mh = w >> 2;                         // KV half
    const int n_tile = qg * 4 + (w & 3);           // q-tile (0..31)
    const int n0 = n_tile * 32;

    for (int rep = 0; rep < REP; ++rep) {
        // launder pointers: forces full recompute every rep (no cross-rep CSE)
        const __hip_bfloat16* qf = qf_in;
        const __hip_bfloat16* kf = kf_in;
        const __hip_bfloat16* vf = vf_in;
        asm volatile("" : "+r"(qf), "+r"(kf), "+r"(vf));

        const __hip_bfloat16* qb = qf + (size_t)(bh * 32 + n_tile) * 1024;
        bf16x8 q0 = *(const bf16x8*)(qb + lane * 8);
        bf16x8 q1 = *(const bf16x8*)(qb + 512 + lane * 8);

        const __hip_bfloat16* kb = kf + (size_t)(bh * 32 + mh * 16) * 1024 + lane * 8;
        const __hip_bfloat16* vb = vf + (size_t)(bh * 32 + mh * 16) * 1024 + lane * 8;

        floatx16 oacc = {0.f,0.f,0.f,0.f,0.f,0.f,0.f,0.f,0.f,0.f,0.f,0.f,0.f,0.f,0.f,0.f};
        float ls0 = 0.f, ls1 = 0.f, ls2 = 0.f, ls3 = 0.f;

        auto body = [&](bf16x8 k0, bf16x8 k1, bf16x8 v0, bf16x8 v1) {
            floatx16 st = {0.f,0.f,0.f,0.f,0.f,0.f,0.f,0.f,0.f,0.f,0.f,0.f,0.f,0.f,0.f,0.f};
            __builtin_amdgcn_s_setprio(1);
            st = __builtin_amdgcn_mfma_f32_32x32x16_bf16(k0, q0, st, 0, 0, 0);
            st = __builtin_amdgcn_mfma_f32_32x32x16_bf16(k1, q1, st, 0, 0, 0);
            __builtin_amdgcn_s_setprio(0);
            float p[16];
            #pragma unroll
            for (int r = 0; r < 16; ++r) p[r] = __builtin_amdgcn_exp2f(st[r]);  // raw v_exp_f32
            ls0 += p[0] + p[4] + p[8]  + p[12];
            ls1 += p[1] + p[5] + p[9]  + p[13];
            ls2 += p[2] + p[6] + p[10] + p[14];
            ls3 += p[3] + p[7] + p[11] + p[15];
            unsigned int wpk[8];
            #pragma unroll
            for (int k2 = 0; k2 < 8; ++k2)
                asm("v_cvt_pk_bf16_f32 %0, %1, %2" : "=v"(wpk[k2]) : "v"(p[2*k2]), "v"(p[2*k2+1]));
            asm("v_permlane32_swap_b32 %0, %1" : "+v"(wpk[0]), "+v"(wpk[2]));
            asm("v_permlane32_swap_b32 %0, %1" : "+v"(wpk[1]), "+v"(wpk[3]));
            asm("v_permlane32_swap_b32 %0, %1" : "+v"(wpk[4]), "+v"(wpk[6]));
            asm("v_permlane32_swap_b32 %0, %1" : "+v"(wpk[5]), "+v"(wpk[7]));
            union { bf16x8 v; unsigned int u[4]; } pb0, pb1;
            pb0.u[0] = wpk[0]; pb0.u[1] = wpk[1]; pb0.u[2] = wpk[2]; pb0.u[3] = wpk[3];
            pb1.u[0] = wpk[4]; pb1.u[1] = wpk[5]; pb1.u[2] = wpk[6]; pb1.u[3] = wpk[7];
            __builtin_amdgcn_s_setprio(1);
            oacc = __builtin_amdgcn_mfma_f32_32x32x16_bf16(v0, pb0.v, oacc, 0, 0, 0);
            oacc = __builtin_amdgcn_mfma_f32_32x32x16_bf16(v1, pb1.v, oacc, 0, 0, 0);
            __builtin_amdgcn_s_setprio(0);
        };

        bf16x8 kc0 = *(const bf16x8*)(kb);
        bf16x8 kc1 = *(const bf16x8*)(kb + 512);
        bf16x8 vc0 = *(const bf16x8*)(vb);
        bf16x8 vc1 = *(const bf16x8*)(vb + 512);
        for (int tt = 0; tt < 8; ++tt) {
            const int tB = tt * 2 + 1, tN = (tt * 2 + 2) & 15;
            bf16x8 kn0 = *(const bf16x8*)(kb + tB * 1024);
            bf16x8 kn1 = *(const bf16x8*)(kb + tB * 1024 + 512);
            bf16x8 vn0 = *(const bf16x8*)(vb + tB * 1024);
            bf16x8 vn1 = *(const bf16x8*)(vb + tB * 1024 + 512);
            body(kc0, kc1, vc0, vc1);
            kc0 = *(const bf16x8*)(kb + tN * 1024);
            kc1 = *(const bf16x8*)(kb + tN * 1024 + 512);
            vc0 = *(const bf16x8*)(vb + tN * 1024);
            vc1 = *(const bf16x8*)(vb + tN * 1024 + 512);
            body(kn0, kn1, vn0, vn1);
        }
        float lsum = (ls0 + ls1) + (ls2 + ls3);

        // merge the two KV-halves (pure sums -- no max state)
        if (w >= 4) {
            #pragma unroll
            for (int r = 0; r < 16; ++r) m_lds[w - 4][lane][r] = oacc[r];
            m_lds[w - 4][lane][16] = lsum;
        }
        __syncthreads();
        if (w < 4) {
            #pragma unroll
            for (int r = 0; r < 16; ++r) oacc[r] += m_lds[w][lane][r];
            lsum += m_lds[w][lane][16];
            lsum += __shfl_xor(lsum, 32);
            float inv = 1.0f / lsum;
            #pragma unroll
            for (int r = 0; r < 16; ++r) {
                int d = (r & 3) + 8 * (r >> 2) + 4 * hi;
                t_lds[w][lc][d] = oacc[r] * inv;
            }
        }
        __syncthreads();
        if (w < 4) {
            const int n_loc = lane >> 1, dh = (lane & 1) * 16;
            union { __hip_bfloat16 h16[16]; uint4 u4[2]; } ov;
            #pragma unroll
            for (int i = 0; i < 16; ++i) ov.h16[i] = __float2bfloat16(t_lds[w][n_loc][dh + i]);
            __hip_bfloat16* dst = obuf + (size_t)(b * NPIX + n0 + n_loc) * CC + h * HD + dh;
            *(uint4*)(dst)     = ov.u4[0];
            *(uint4*)(dst + 8) = ov.u4[1];
        }
        __syncthreads();       // protect m_lds/t_lds across reps
    }
}

// ---------------------------------------------------------------- proj + residual (unchanged)
__global__ __launch_bounds__(256) void gemm_proj_res(const __hip_bfloat16* __restrict__ obuf,
                                                     const __hip_bfloat16* __restrict__ wp,
                                                     const float* __restrict__ bp,
                                                     const float* __restrict__ x,
                                                     float* __restrict__ out) {
    const int c0 = blockIdx.x * 64, n0 = blockIdx.y * 64, b = blockIdx.z;
    const int tid = threadIdx.x, w = tid >> 6, lane = tid & 63;
    const int lr = lane & 15, lg = lane >> 4;

    floatx4 acc[4] = {};
    const size_t arow = (size_t)(c0 + w * 16 + lr) * CC;
    for (int kk = 0; kk < CC; kk += 32) {
        bf16x8 a = *(const bf16x8*)(wp + arow + kk + lg * 8);
        for (int nt = 0; nt < 4; ++nt) {
            bf16x8 bfr = *(const bf16x8*)(obuf + (size_t)(b * NPIX + n0 + nt * 16 + lr) * CC + kk + lg * 8);
            acc[nt] = __builtin_amdgcn_mfma_f32_16x16x32_bf16(a, bfr, acc[nt], 0, 0, 0);
        }
    }
    for (int nt = 0; nt < 4; ++nt)
        for (int r = 0; r < 4; ++r) {
            int c = c0 + w * 16 + lg * 4 + r;
            int n = n0 + nt * 16 + lr;
            size_t idx = ((size_t)b * CC + c) * NPIX + n;
            out[idx] = acc[nt][r] + bp[c] + x[idx];
        }
}

// ---------------------------------------------------------------- launch
extern "C" void kernel_launch(void* const* d_in, const int* in_sizes, int n_in,
                              void* d_out, int out_size, void* d_ws, size_t ws_size,
                              hipStream_t stream) {
    const float* x      = (const float*)d_in[0];
    const float* gamma  = (const float*)d_in[1];
    const float* beta   = (const float*)d_in[2];
    const float* w_qkv  = (const float*)d_in[3];
    const float* b_qkv  = (const float*)d_in[4];
    const float* w_proj = (const float*)d_in[5];
    const float* b_proj = (const float*)d_in[6];
    float* out = (float*)d_out;

    char* ws = (char*)d_ws;
    __hip_bfloat16* qfb  = (__hip_bfloat16*)(ws);                            // 4 MB
    __hip_bfloat16* kfb  = (__hip_bfloat16*)(ws + (4  << 20));               // 4 MB
    __hip_bfloat16* vfb  = (__hip_bfloat16*)(ws + (8  << 20));               // 4 MB
    __hip_bfloat16* obuf = (__hip_bfloat16*)(ws + (12 << 20));               // 4 MB  [8192][256]
    __hip_bfloat16* wqb  = (__hip_bfloat16*)(ws + (16 << 20));               // 384 KB
    __hip_bfloat16* wpb  = (__hip_bfloat16*)(ws + (16 << 20) + (512 << 10)); // 128 KB

    f2b_cvt2<<<(QKVO * CC + CC * CC + 255) / 256, 256, 0, stream>>>(w_qkv, wqb, QKVO * CC,
                                                                    w_proj, wpb, CC * CC);
    ln_qkv<<<BB * NPIX / 32, 512, 0, stream>>>(x, gamma, beta, wqb, b_qkv, qfb, kfb, vfb);
    attn_probe<<<dim3(64, 8), 512, 0, stream>>>(qfb, kfb, vfb, obuf);
    gemm_proj_res<<<dim3(CC / 64, NPIX / 64, BB), 256, 0, stream>>>(obuf, wpb, b_proj, x, out);
}

// Round 9
// 94.450 us; speedup vs baseline: 1.0929x; 1.0929x over previous
//
#include <hip/hip_runtime.h>
#include <hip/hip_bf16.h>

// Problem constants (B,C,H,W)=(8,256,32,32), heads=8, head_dim=32
#define BB 8
#define CC 256
#define NPIX 1024          // H*W
#define NH 8
#define HD 32
#define QKVO 768           // 3*256
#define EPS 1e-5f

typedef __attribute__((ext_vector_type(4)))  float floatx4;
typedef __attribute__((ext_vector_type(16))) float floatx16;
typedef __attribute__((ext_vector_type(8)))  short bf16x8;

// Q/K/V are stored in MFMA-fragment order:
//   frag buffer block for (bh, tile32) = 1024 bf16 = [sub(2)][lane(64)][elem(8)]
//   Q (B-op): lane = (n&31) + 32*((d>>3)&1), sub = d>>4,        elem = d&7
//   K (A-op): lane = (m&31) + 32*((d>>3)&1), sub = d>>4,        elem = d&7
//   V (A-op): lane = d      + 32*((m&15)>>3), sub = (m&31)>>4,  elem = m&7
// Q is pre-scaled by head_dim^-0.5 * log2(e) so softmax is p = 2^st.

// ---------------------------------------------------------------- fused LN + QKV GEMM -> fragment buffers
// (weights read as f32 and converted in-flight: f2b kernel eliminated)
__global__ __launch_bounds__(512) void ln_qkv(const float* __restrict__ x,
                                              const float* __restrict__ gamma,
                                              const float* __restrict__ beta,
                                              const float* __restrict__ wq,
                                              const float* __restrict__ bq,
                                              __hip_bfloat16* __restrict__ qf,
                                              __hip_bfloat16* __restrict__ kf,
                                              __hip_bfloat16* __restrict__ vf) {
    __shared__ short xbn[32 * 256];      // 16 KB normalized tile, swizzled
    __shared__ float s_part[16][33];
    __shared__ float q_part[16][33];
    __shared__ float s_mu[32], s_rs[32];

    const int tid  = threadIdx.x;
    const int P0   = blockIdx.x * 32;    // global pixel base (32 | 1024: no batch straddle)
    const int b    = P0 >> 10;
    const int nloc = tid & 31;
    const int g    = tid >> 5;           // 0..15
    const float* xb = x + (size_t)b * CC * NPIX + (P0 & 1023);

    // ---- Phase A: stats; load exactly the 16 channels phase B will emit,
    //      keep them in registers (channels g*8..+7 and 128+g*8..+7)
    float vals[16];
    float s = 0.f, s2 = 0.f;
    #pragma unroll
    for (int j = 0; j < 8; ++j) {
        float v = xb[(size_t)(g * 8 + j) * NPIX + nloc];
        vals[j] = v; s += v; s2 += v * v;
    }
    #pragma unroll
    for (int j = 0; j < 8; ++j) {
        float v = xb[(size_t)(128 + g * 8 + j) * NPIX + nloc];
        vals[8 + j] = v; s += v; s2 += v * v;
    }
    s_part[g][nloc] = s; q_part[g][nloc] = s2;
    __syncthreads();
    if (tid < 32) {
        float ss = 0.f, qq = 0.f;
        #pragma unroll
        for (int k = 0; k < 16; ++k) { ss += s_part[k][tid]; qq += q_part[k][tid]; }
        float mu  = ss * (1.f / CC);
        float var = qq * (1.f / CC) - mu * mu;
        s_mu[tid] = mu; s_rs[tid] = rsqrtf(var + EPS);
    }
    __syncthreads();

    // ---- Phase B: normalize from registers -> swizzled LDS bf16
    {
        const float mu = s_mu[nloc], rs = s_rs[nloc];
        #pragma unroll
        for (int half = 0; half < 2; ++half) {
            int cb = g + half * 16;            // 8-channel block index
            union { bf16x8 v; unsigned short us[8]; } pk;
            #pragma unroll
            for (int j = 0; j < 8; ++j) {
                int c = cb * 8 + j;
                float v = vals[half * 8 + j];
                pk.us[j] = __bfloat16_as_ushort(__float2bfloat16((v - mu) * rs * gamma[c] + beta[c]));
            }
            int idx = (nloc * 256 + cb * 8) ^ ((nloc & 31) << 3);
            *(bf16x8*)(&xbn[idx]) = pk.v;
        }
    }
    __syncthreads();

    // ---- Phase C: GEMM 32 x 768 x 256  (B-operand: f32 weights, cvt in-flight)
    const int w = tid >> 6, lane = tid & 63, lr = lane & 15, lg = lane >> 4;
    const int mstrip = (w & 1) * 16;        // two 16-row strips
    const int ob     = (w >> 1) * 192;      // four o-blocks of 192 (= 2 heads)
    floatx4 acc[12] = {};
    for (int kk = 0; kk < CC; kk += 32) {
        const int arow = mstrip + lr;
        const int aidx = (arow * 256 + kk + lg * 8) ^ ((arow & 31) << 3);
        bf16x8 a = *(const bf16x8*)(&xbn[aidx]);
        #pragma unroll
        for (int nt = 0; nt < 12; ++nt) {
            const int o = ob + nt * 16 + lr;
            const float* wr = wq + (size_t)o * CC + kk + lg * 8;
            floatx4 wlo = *(const floatx4*)(wr);
            floatx4 whi = *(const floatx4*)(wr + 4);
            union { bf16x8 v; __hip_bfloat16 h[8]; } bb;
            #pragma unroll
            for (int j = 0; j < 4; ++j) {
                bb.h[j]     = __float2bfloat16(wlo[j]);
                bb.h[4 + j] = __float2bfloat16(whi[j]);
            }
            acc[nt] = __builtin_amdgcn_mfma_f32_16x16x32_bf16(a, bb.v, acc[nt], 0, 0, 0);
        }
    }
    // ---- epilogue: write fragment-order Q/K/V.  Q is pre-scaled by
    //      head_dim^-0.5 * log2(e) so attention's softmax is p = 2^st.
    const float QSCALE = 0.25503495f;       // 0.17677669529663689 * 1.4426950408889634
    const int m_base = mstrip + lg * 4;     // m_in base (0..28, mult of 4)
    const int tile   = blockIdx.x & 31;     // pixel tile within image
    #pragma unroll
    for (int nt = 0; nt < 12; ++nt) {
        const int o = ob + nt * 16 + lr;
        const int h = o / 96, om = o % 96;  // uniform per nt across the 16-lane run
        const float bias = bq[o];
        const size_t fb = (size_t)((b * NH + h) * 32 + tile) * 1024;
        if (om < 64) {                      // Q or K: 4 scalar 2B stores (lane varies with m)
            const int d = om & 31;
            const bool isq = (om < 32);
            __hip_bfloat16* dst = (isq ? qf : kf);
            const float sc = isq ? QSCALE : 1.0f;
            const int off = (d >> 4) * 512 + ((d >> 3) & 1) * 256 + (d & 7);
            #pragma unroll
            for (int r = 0; r < 4; ++r)
                dst[fb + off + (m_base + r) * 8] = __float2bfloat16((acc[nt][r] + bias) * sc);
        } else {                            // V: 4 consecutive m -> one uint2 store
            const int d = om - 64;
            const int half = m_base >> 4, hi = (m_base >> 3) & 1, j0 = m_base & 7;
            union { unsigned short us[4]; uint2 u; } pv;
            #pragma unroll
            for (int r = 0; r < 4; ++r)
                pv.us[r] = __bfloat16_as_ushort(__float2bfloat16(acc[nt][r] + bias));
            *(uint2*)(vf + fb + half * 512 + (d + 32 * hi) * 8 + j0) = pv.u;
        }
    }
}

// ---------------------------------------------------------------- attention v7
// Probe counters (R7): VALUBusy 49%, MfmaUtil 24%, Occupancy 34% -> latency/
// occupancy-bound. Fix: 4-way KV split, 16-wave (1024-thr) blocks, grid 512
// -> 32 waves/CU (2 blocks/CU; VGPR<=64 via launch_bounds(1024,8), body
// measured at 48). 4-way merge through LDS; m_lds/t_lds aliased (52 KB).
__global__ __launch_bounds__(1024, 8) void attn_fused7(const __hip_bfloat16* __restrict__ qf,
                                                       const __hip_bfloat16* __restrict__ kf,
                                                       const __hip_bfloat16* __restrict__ vf,
                                                       __hip_bfloat16* __restrict__ obuf) {
    __shared__ float smem_f[3 * 4 * 64 * 17];          // 52224 B, aliased phases
    float (*m_lds)[4][64][17] = (float (*)[4][64][17]) smem_f;  // [3][4][64][17]
    float (*t_lds)[32][33]    = (float (*)[32][33])    smem_f;  // [4][32][33]

    // XCD-bijective remap: XCD j hosts bh in {8j..8j+7}
    const int flat = blockIdx.y * 64 + blockIdx.x;          // 0..511
    const int bh   = (flat & 7) * 8 + ((flat >> 3) & 7);
    const int qg   = flat >> 6;                             // 0..7
    const int b = bh >> 3, h = bh & 7;
    const int tid = threadIdx.x, w = tid >> 6, lane = tid & 63;
    const int lc = lane & 31, hi = lane >> 5;
    const int kq = w >> 2;                         // KV quarter (0..3)
    const int qt = w & 3;                          // q-tile within group
    const int n_tile = qg * 4 + qt;                // q-tile (0..31)
    const int n0 = n_tile * 32;

    const __hip_bfloat16* qb = qf + (size_t)(bh * 32 + n_tile) * 1024;
    bf16x8 q0 = *(const bf16x8*)(qb + lane * 8);
    bf16x8 q1 = *(const bf16x8*)(qb + 512 + lane * 8);

    const __hip_bfloat16* kb = kf + (size_t)(bh * 32 + kq * 8) * 1024 + lane * 8;
    const __hip_bfloat16* vb = vf + (size_t)(bh * 32 + kq * 8) * 1024 + lane * 8;

    floatx16 oacc = {0.f,0.f,0.f,0.f,0.f,0.f,0.f,0.f,0.f,0.f,0.f,0.f,0.f,0.f,0.f,0.f};
    float ls0 = 0.f, ls1 = 0.f, ls2 = 0.f, ls3 = 0.f;

    #pragma unroll 2
    for (int t = 0; t < 8; ++t) {
        bf16x8 k0 = *(const bf16x8*)(kb + t * 1024);
        bf16x8 k1 = *(const bf16x8*)(kb + t * 1024 + 512);
        bf16x8 v0 = *(const bf16x8*)(vb + t * 1024);
        bf16x8 v1 = *(const bf16x8*)(vb + t * 1024 + 512);

        floatx16 st = {0.f,0.f,0.f,0.f,0.f,0.f,0.f,0.f,0.f,0.f,0.f,0.f,0.f,0.f,0.f,0.f};
        __builtin_amdgcn_s_setprio(1);
        st = __builtin_amdgcn_mfma_f32_32x32x16_bf16(k0, q0, st, 0, 0, 0);
        st = __builtin_amdgcn_mfma_f32_32x32x16_bf16(k1, q1, st, 0, 0, 0);
        __builtin_amdgcn_s_setprio(0);
        float p[16];
        #pragma unroll
        for (int r = 0; r < 16; ++r) p[r] = __builtin_amdgcn_exp2f(st[r]);   // raw v_exp_f32
        ls0 += p[0] + p[4] + p[8]  + p[12];
        ls1 += p[1] + p[5] + p[9]  + p[13];
        ls2 += p[2] + p[6] + p[10] + p[14];
        ls3 += p[3] + p[7] + p[11] + p[15];
        unsigned int wpk[8];
        #pragma unroll
        for (int k2 = 0; k2 < 8; ++k2)
            asm("v_cvt_pk_bf16_f32 %0, %1, %2" : "=v"(wpk[k2]) : "v"(p[2*k2]), "v"(p[2*k2+1]));
        asm("v_permlane32_swap_b32 %0, %1" : "+v"(wpk[0]), "+v"(wpk[2]));
        asm("v_permlane32_swap_b32 %0, %1" : "+v"(wpk[1]), "+v"(wpk[3]));
        asm("v_permlane32_swap_b32 %0, %1" : "+v"(wpk[4]), "+v"(wpk[6]));
        asm("v_permlane32_swap_b32 %0, %1" : "+v"(wpk[5]), "+v"(wpk[7]));
        union { bf16x8 v; unsigned int u[4]; } pb0, pb1;
        pb0.u[0] = wpk[0]; pb0.u[1] = wpk[1]; pb0.u[2] = wpk[2]; pb0.u[3] = wpk[3];
        pb1.u[0] = wpk[4]; pb1.u[1] = wpk[5]; pb1.u[2] = wpk[6]; pb1.u[3] = wpk[7];
        __builtin_amdgcn_s_setprio(1);
        oacc = __builtin_amdgcn_mfma_f32_32x32x16_bf16(v0, pb0.v, oacc, 0, 0, 0);
        oacc = __builtin_amdgcn_mfma_f32_32x32x16_bf16(v1, pb1.v, oacc, 0, 0, 0);
        __builtin_amdgcn_s_setprio(0);
    }
    float lsum = (ls0 + ls1) + (ls2 + ls3);

    // ---- 4-way KV merge (pure sums -- no max state)
    if (kq > 0) {
        #pragma unroll
        for (int r = 0; r < 16; ++r) m_lds[kq - 1][qt][lane][r] = oacc[r];
        m_lds[kq - 1][qt][lane][16] = lsum;
    }
    __syncthreads();
    float inv = 0.f;
    if (kq == 0) {
        #pragma unroll
        for (int s = 0; s < 3; ++s) {
            #pragma unroll
            for (int r = 0; r < 16; ++r) oacc[r] += m_lds[s][qt][lane][r];
            lsum += m_lds[s][qt][lane][16];
        }
        lsum += __shfl_xor(lsum, 32);
        inv = 1.0f / lsum;
    }
    __syncthreads();          // all m_lds reads done; smem re-used as t_lds
    if (kq == 0) {
        #pragma unroll
        for (int r = 0; r < 16; ++r) {
            int d = (r & 3) + 8 * (r >> 2) + 4 * hi;
            t_lds[qt][lc][d] = oacc[r] * inv;
        }
    }
    __syncthreads();
    if (kq == 0) {
        const int n_loc = lane >> 1, dh = (lane & 1) * 16;
        union { __hip_bfloat16 h16[16]; uint4 u4[2]; } ov;
        #pragma unroll
        for (int i = 0; i < 16; ++i) ov.h16[i] = __float2bfloat16(t_lds[qt][n_loc][dh + i]);
        __hip_bfloat16* dst = obuf + (size_t)(b * NPIX + n0 + n_loc) * CC + h * HD + dh;
        *(uint4*)(dst)     = ov.u4[0];
        *(uint4*)(dst + 8) = ov.u4[1];
    }
}

// ---------------------------------------------------------------- proj + residual
// (weights read as f32 and converted in-flight)
__global__ __launch_bounds__(256) void gemm_proj_res(const __hip_bfloat16* __restrict__ obuf,
                                                     const float* __restrict__ wp,
                                                     const float* __restrict__ bp,
                                                     const float* __restrict__ x,
                                                     float* __restrict__ out) {
    const int c0 = blockIdx.x * 64, n0 = blockIdx.y * 64, b = blockIdx.z;
    const int tid = threadIdx.x, w = tid >> 6, lane = tid & 63;
    const int lr = lane & 15, lg = lane >> 4;

    floatx4 acc[4] = {};
    const size_t arow = (size_t)(c0 + w * 16 + lr) * CC;
    for (int kk = 0; kk < CC; kk += 32) {
        const float* wr = wp + arow + kk + lg * 8;
        floatx4 wlo = *(const floatx4*)(wr);
        floatx4 whi = *(const floatx4*)(wr + 4);
        union { bf16x8 v; __hip_bfloat16 h[8]; } aa;
        #pragma unroll
        for (int j = 0; j < 4; ++j) {
            aa.h[j]     = __float2bfloat16(wlo[j]);
            aa.h[4 + j] = __float2bfloat16(whi[j]);
        }
        #pragma unroll
        for (int nt = 0; nt < 4; ++nt) {
            bf16x8 bfr = *(const bf16x8*)(obuf + (size_t)(b * NPIX + n0 + nt * 16 + lr) * CC + kk + lg * 8);
            acc[nt] = __builtin_amdgcn_mfma_f32_16x16x32_bf16(aa.v, bfr, acc[nt], 0, 0, 0);
        }
    }
    #pragma unroll
    for (int nt = 0; nt < 4; ++nt)
        #pragma unroll
        for (int r = 0; r < 4; ++r) {
            int c = c0 + w * 16 + lg * 4 + r;
            int n = n0 + nt * 16 + lr;
            size_t idx = ((size_t)b * CC + c) * NPIX + n;
            out[idx] = acc[nt][r] + bp[c] + x[idx];
        }
}

// ---------------------------------------------------------------- launch
extern "C" void kernel_launch(void* const* d_in, const int* in_sizes, int n_in,
                              void* d_out, int out_size, void* d_ws, size_t ws_size,
                              hipStream_t stream) {
    const float* x      = (const float*)d_in[0];
    const float* gamma  = (const float*)d_in[1];
    const float* beta   = (const float*)d_in[2];
    const float* w_qkv  = (const float*)d_in[3];
    const float* b_qkv  = (const float*)d_in[4];
    const float* w_proj = (const float*)d_in[5];
    const float* b_proj = (const float*)d_in[6];
    float* out = (float*)d_out;

    char* ws = (char*)d_ws;
    __hip_bfloat16* qfb  = (__hip_bfloat16*)(ws);                            // 4 MB
    __hip_bfloat16* kfb  = (__hip_bfloat16*)(ws + (4  << 20));               // 4 MB
    __hip_bfloat16* vfb  = (__hip_bfloat16*)(ws + (8  << 20));               // 4 MB
    __hip_bfloat16* obuf = (__hip_bfloat16*)(ws + (12 << 20));               // 4 MB  [8192][256]

    ln_qkv<<<BB * NPIX / 32, 512, 0, stream>>>(x, gamma, beta, w_qkv, b_qkv, qfb, kfb, vfb);
    attn_fused7<<<dim3(64, 8), 1024, 0, stream>>>(qfb, kfb, vfb, obuf);
    gemm_proj_res<<<dim3(CC / 64, NPIX / 64, BB), 256, 0, stream>>>(obuf, w_proj, b_proj, x, out);
}

// Round 10
// 57.667 us; speedup vs baseline: 1.7899x; 1.6378x over previous
//
#include <hip/hip_runtime.h>
#include <hip/hip_bf16.h>

// Problem constants (B,C,H,W)=(8,256,32,32), heads=8, head_dim=32
#define BB 8
#define CC 256
#define NPIX 1024          // H*W
#define NH 8
#define HD 32
#define QKVO 768           // 3*256
#define EPS 1e-5f

typedef __attribute__((ext_vector_type(4)))  float floatx4;
typedef __attribute__((ext_vector_type(16))) float floatx16;
typedef __attribute__((ext_vector_type(8)))  short bf16x8;

// Q/K/V frag layout (per (bh,tile32) block of 1024 bf16 = [sub2][lane64][elem8]):
//   Q (B-op): lane = (n&31) + 32*((d>>3)&1), sub = d>>4,        elem = d&7
//   K (A-op): lane = (m&31) + 32*((d>>3)&1), sub = d>>4,        elem = d&7
//   V (A-op): lane = d      + 32*((m&15)>>3), sub = (m&31)>>4,  elem = m&7
// Q is pre-scaled by head_dim^-0.5 * log2(e) so softmax is p = 2^st.
//
// Weight frag layout (16x16x32 A/B operand, identical mapping):
//   wf[((tile*8 + kks)*64 + lane)*8 + j]  holds  W[tile*16 + (lane&15)]
//                                               [kks*32 + (lane>>4)*8 + j]
// -> every weight fragment load is a contiguous lane*16B chunk (no gather).

// ---------------------------------------------------------------- weight prep: f32 row-major -> bf16 frag order
// w_qkv [768][256] -> wqf (48 tiles); w_proj [256][256] -> wpf (16 tiles).
// 32768 threads, each writes one 16B frag chunk.
__global__ __launch_bounds__(256) void w_prep(const float* __restrict__ wq,
                                              const float* __restrict__ wp,
                                              __hip_bfloat16* __restrict__ wqf,
                                              __hip_bfloat16* __restrict__ wpf) {
    int idx = blockIdx.x * 256 + threadIdx.x;          // 0..32767
    const float* src;
    __hip_bfloat16* dst;
    int n;
    if (idx < 24576) { src = wq; dst = wqf; n = idx; }           // 48*8*64
    else             { src = wp; dst = wpf; n = idx - 24576; }   // 16*8*64
    const int lane = n & 63, kks = (n >> 6) & 7, tile = n >> 9;
    const int row = tile * 16 + (lane & 15);
    const int col = kks * 32 + (lane >> 4) * 8;
    const float* s = src + (size_t)row * CC + col;
    union { bf16x8 v; __hip_bfloat16 h[8]; } pk;
    #pragma unroll
    for (int j = 0; j < 8; ++j) pk.h[j] = __float2bfloat16(s[j]);
    *(bf16x8*)(dst + (size_t)n * 8) = pk.v;
}

// ---------------------------------------------------------------- fused LN + QKV GEMM -> fragment buffers
__global__ __launch_bounds__(512) void ln_qkv(const float* __restrict__ x,
                                              const float* __restrict__ gamma,
                                              const float* __restrict__ beta,
                                              const __hip_bfloat16* __restrict__ wqf,
                                              const float* __restrict__ bq,
                                              __hip_bfloat16* __restrict__ qf,
                                              __hip_bfloat16* __restrict__ kf,
                                              __hip_bfloat16* __restrict__ vf) {
    __shared__ short xbn[32 * 256];      // 16 KB normalized tile, swizzled
    __shared__ float s_part[16][33];
    __shared__ float q_part[16][33];
    __shared__ float s_mu[32], s_rs[32];

    const int tid  = threadIdx.x;
    const int P0   = blockIdx.x * 32;    // global pixel base (32 | 1024: no batch straddle)
    const int b    = P0 >> 10;
    const int nloc = tid & 31;
    const int g    = tid >> 5;           // 0..15
    const float* xb = x + (size_t)b * CC * NPIX + (P0 & 1023);

    // ---- Phase A: stats; load exactly the 16 channels phase B will emit
    float vals[16];
    float s = 0.f, s2 = 0.f;
    #pragma unroll
    for (int j = 0; j < 8; ++j) {
        float v = xb[(size_t)(g * 8 + j) * NPIX + nloc];
        vals[j] = v; s += v; s2 += v * v;
    }
    #pragma unroll
    for (int j = 0; j < 8; ++j) {
        float v = xb[(size_t)(128 + g * 8 + j) * NPIX + nloc];
        vals[8 + j] = v; s += v; s2 += v * v;
    }
    s_part[g][nloc] = s; q_part[g][nloc] = s2;
    __syncthreads();
    if (tid < 32) {
        float ss = 0.f, qq = 0.f;
        #pragma unroll
        for (int k = 0; k < 16; ++k) { ss += s_part[k][tid]; qq += q_part[k][tid]; }
        float mu  = ss * (1.f / CC);
        float var = qq * (1.f / CC) - mu * mu;
        s_mu[tid] = mu; s_rs[tid] = rsqrtf(var + EPS);
    }
    __syncthreads();

    // ---- Phase B: normalize from registers -> swizzled LDS bf16
    {
        const float mu = s_mu[nloc], rs = s_rs[nloc];
        #pragma unroll
        for (int half = 0; half < 2; ++half) {
            int cb = g + half * 16;            // 8-channel block index
            union { bf16x8 v; unsigned short us[8]; } pk;
            #pragma unroll
            for (int j = 0; j < 8; ++j) {
                int c = cb * 8 + j;
                float v = vals[half * 8 + j];
                pk.us[j] = __bfloat16_as_ushort(__float2bfloat16((v - mu) * rs * gamma[c] + beta[c]));
            }
            int idx = (nloc * 256 + cb * 8) ^ ((nloc & 31) << 3);
            *(bf16x8*)(&xbn[idx]) = pk.v;
        }
    }
    __syncthreads();

    // ---- Phase C: GEMM 32 x 768 x 256, weights from frag buffer (contiguous)
    const int w = tid >> 6, lane = tid & 63, lr = lane & 15, lg = lane >> 4;
    const int mstrip = (w & 1) * 16;        // two 16-row strips
    const int otb    = (w >> 1) * 12;       // o-tile base (12 tiles = 192 outputs)
    floatx4 acc[12] = {};
    for (int kks = 0; kks < 8; ++kks) {
        const int arow = mstrip + lr;
        const int aidx = (arow * 256 + kks * 32 + lg * 8) ^ ((arow & 31) << 3);
        bf16x8 a = *(const bf16x8*)(&xbn[aidx]);
        #pragma unroll
        for (int nt = 0; nt < 12; ++nt) {
            bf16x8 bfr = *(const bf16x8*)(wqf + (((size_t)(otb + nt) * 8 + kks) * 64 + lane) * 8);
            acc[nt] = __builtin_amdgcn_mfma_f32_16x16x32_bf16(a, bfr, acc[nt], 0, 0, 0);
        }
    }
    // ---- epilogue: write fragment-order Q/K/V.  Q pre-scaled by scale*log2e.
    const float QSCALE = 0.25503495f;       // 0.17677669529663689 * 1.4426950408889634
    const int m_base = mstrip + lg * 4;     // m_in base (0..28, mult of 4)
    const int tile   = blockIdx.x & 31;     // pixel tile within image
    #pragma unroll
    for (int nt = 0; nt < 12; ++nt) {
        const int o = (otb + nt) * 16 + lr;
        const int h = o / 96, om = o % 96;  // uniform per nt across the 16-lane run
        const float bias = bq[o];
        const size_t fb = (size_t)((b * NH + h) * 32 + tile) * 1024;
        if (om < 64) {                      // Q or K: 4 scalar 2B stores (lane varies with m)
            const int d = om & 31;
            const bool isq = (om < 32);
            __hip_bfloat16* dst = (isq ? qf : kf);
            const float sc = isq ? QSCALE : 1.0f;
            const int off = (d >> 4) * 512 + ((d >> 3) & 1) * 256 + (d & 7);
            #pragma unroll
            for (int r = 0; r < 4; ++r)
                dst[fb + off + (m_base + r) * 8] = __float2bfloat16((acc[nt][r] + bias) * sc);
        } else {                            // V: 4 consecutive m -> one uint2 store
            const int d = om - 64;
            const int half = m_base >> 4, hi = (m_base >> 3) & 1, j0 = m_base & 7;
            union { unsigned short us[4]; uint2 u; } pv;
            #pragma unroll
            for (int r = 0; r < 4; ++r)
                pv.us[r] = __bfloat16_as_ushort(__float2bfloat16(acc[nt][r] + bias));
            *(uint2*)(vf + fb + half * 512 + (d + 32 * hi) * 8 + j0) = pv.u;
        }
    }
}

// ---------------------------------------------------------------- attention v7 (unchanged from R8)
__global__ __launch_bounds__(1024, 8) void attn_fused7(const __hip_bfloat16* __restrict__ qf,
                                                       const __hip_bfloat16* __restrict__ kf,
                                                       const __hip_bfloat16* __restrict__ vf,
                                                       __hip_bfloat16* __restrict__ obuf) {
    __shared__ float smem_f[3 * 4 * 64 * 17];          // 52224 B, aliased phases
    float (*m_lds)[4][64][17] = (float (*)[4][64][17]) smem_f;  // [3][4][64][17]
    float (*t_lds)[32][33]    = (float (*)[32][33])    smem_f;  // [4][32][33]

    const int flat = blockIdx.y * 64 + blockIdx.x;          // 0..511
    const int bh   = (flat & 7) * 8 + ((flat >> 3) & 7);    // XCD-bijective remap
    const int qg   = flat >> 6;                             // 0..7
    const int b = bh >> 3, h = bh & 7;
    const int tid = threadIdx.x, w = tid >> 6, lane = tid & 63;
    const int lc = lane & 31, hi = lane >> 5;
    const int kq = w >> 2;                         // KV quarter (0..3)
    const int qt = w & 3;                          // q-tile within group
    const int n_tile = qg * 4 + qt;                // q-tile (0..31)
    const int n0 = n_tile * 32;

    const __hip_bfloat16* qb = qf + (size_t)(bh * 32 + n_tile) * 1024;
    bf16x8 q0 = *(const bf16x8*)(qb + lane * 8);
    bf16x8 q1 = *(const bf16x8*)(qb + 512 + lane * 8);

    const __hip_bfloat16* kb = kf + (size_t)(bh * 32 + kq * 8) * 1024 + lane * 8;
    const __hip_bfloat16* vb = vf + (size_t)(bh * 32 + kq * 8) * 1024 + lane * 8;

    floatx16 oacc = {0.f,0.f,0.f,0.f,0.f,0.f,0.f,0.f,0.f,0.f,0.f,0.f,0.f,0.f,0.f,0.f};
    float ls0 = 0.f, ls1 = 0.f, ls2 = 0.f, ls3 = 0.f;

    #pragma unroll 2
    for (int t = 0; t < 8; ++t) {
        bf16x8 k0 = *(const bf16x8*)(kb + t * 1024);
        bf16x8 k1 = *(const bf16x8*)(kb + t * 1024 + 512);
        bf16x8 v0 = *(const bf16x8*)(vb + t * 1024);
        bf16x8 v1 = *(const bf16x8*)(vb + t * 1024 + 512);

        floatx16 st = {0.f,0.f,0.f,0.f,0.f,0.f,0.f,0.f,0.f,0.f,0.f,0.f,0.f,0.f,0.f,0.f};
        __builtin_amdgcn_s_setprio(1);
        st = __builtin_amdgcn_mfma_f32_32x32x16_bf16(k0, q0, st, 0, 0, 0);
        st = __builtin_amdgcn_mfma_f32_32x32x16_bf16(k1, q1, st, 0, 0, 0);
        __builtin_amdgcn_s_setprio(0);
        float p[16];
        #pragma unroll
        for (int r = 0; r < 16; ++r) p[r] = __builtin_amdgcn_exp2f(st[r]);   // raw v_exp_f32
        ls0 += p[0] + p[4] + p[8]  + p[12];
        ls1 += p[1] + p[5] + p[9]  + p[13];
        ls2 += p[2] + p[6] + p[10] + p[14];
        ls3 += p[3] + p[7] + p[11] + p[15];
        unsigned int wpk[8];
        #pragma unroll
        for (int k2 = 0; k2 < 8; ++k2)
            asm("v_cvt_pk_bf16_f32 %0, %1, %2" : "=v"(wpk[k2]) : "v"(p[2*k2]), "v"(p[2*k2+1]));
        asm("v_permlane32_swap_b32 %0, %1" : "+v"(wpk[0]), "+v"(wpk[2]));
        asm("v_permlane32_swap_b32 %0, %1" : "+v"(wpk[1]), "+v"(wpk[3]));
        asm("v_permlane32_swap_b32 %0, %1" : "+v"(wpk[4]), "+v"(wpk[6]));
        asm("v_permlane32_swap_b32 %0, %1" : "+v"(wpk[5]), "+v"(wpk[7]));
        union { bf16x8 v; unsigned int u[4]; } pb0, pb1;
        pb0.u[0] = wpk[0]; pb0.u[1] = wpk[1]; pb0.u[2] = wpk[2]; pb0.u[3] = wpk[3];
        pb1.u[0] = wpk[4]; pb1.u[1] = wpk[5]; pb1.u[2] = wpk[6]; pb1.u[3] = wpk[7];
        __builtin_amdgcn_s_setprio(1);
        oacc = __builtin_amdgcn_mfma_f32_32x32x16_bf16(v0, pb0.v, oacc, 0, 0, 0);
        oacc = __builtin_amdgcn_mfma_f32_32x32x16_bf16(v1, pb1.v, oacc, 0, 0, 0);
        __builtin_amdgcn_s_setprio(0);
    }
    float lsum = (ls0 + ls1) + (ls2 + ls3);

    // ---- 4-way KV merge (pure sums -- no max state)
    if (kq > 0) {
        #pragma unroll
        for (int r = 0; r < 16; ++r) m_lds[kq - 1][qt][lane][r] = oacc[r];
        m_lds[kq - 1][qt][lane][16] = lsum;
    }
    __syncthreads();
    float inv = 0.f;
    if (kq == 0) {
        #pragma unroll
        for (int s = 0; s < 3; ++s) {
            #pragma unroll
            for (int r = 0; r < 16; ++r) oacc[r] += m_lds[s][qt][lane][r];
            lsum += m_lds[s][qt][lane][16];
        }
        lsum += __shfl_xor(lsum, 32);
        inv = 1.0f / lsum;
    }
    __syncthreads();          // all m_lds reads done; smem re-used as t_lds
    if (kq == 0) {
        #pragma unroll
        for (int r = 0; r < 16; ++r) {
            int d = (r & 3) + 8 * (r >> 2) + 4 * hi;
            t_lds[qt][lc][d] = oacc[r] * inv;
        }
    }
    __syncthreads();
    if (kq == 0) {
        const int n_loc = lane >> 1, dh = (lane & 1) * 16;
        union { __hip_bfloat16 h16[16]; uint4 u4[2]; } ov;
        #pragma unroll
        for (int i = 0; i < 16; ++i) ov.h16[i] = __float2bfloat16(t_lds[qt][n_loc][dh + i]);
        __hip_bfloat16* dst = obuf + (size_t)(b * NPIX + n0 + n_loc) * CC + h * HD + dh;
        *(uint4*)(dst)     = ov.u4[0];
        *(uint4*)(dst + 8) = ov.u4[1];
    }
}

// ---------------------------------------------------------------- proj + residual (weights from frag buffer)
__global__ __launch_bounds__(256) void gemm_proj_res(const __hip_bfloat16* __restrict__ obuf,
                                                     const __hip_bfloat16* __restrict__ wpf,
                                                     const float* __restrict__ bp,
                                                     const float* __restrict__ x,
                                                     float* __restrict__ out) {
    const int c0 = blockIdx.x * 64, n0 = blockIdx.y * 64, b = blockIdx.z;
    const int tid = threadIdx.x, w = tid >> 6, lane = tid & 63;
    const int lr = lane & 15, lg = lane >> 4;
    const int ct = (c0 >> 4) + w;           // this wave's c-tile (16 rows)

    floatx4 acc[4] = {};
    for (int kks = 0; kks < 8; ++kks) {
        bf16x8 aa = *(const bf16x8*)(wpf + (((size_t)ct * 8 + kks) * 64 + lane) * 8);
        #pragma unroll
        for (int nt = 0; nt < 4; ++nt) {
            bf16x8 bfr = *(const bf16x8*)(obuf + (size_t)(b * NPIX + n0 + nt * 16 + lr) * CC + kks * 32 + lg * 8);
            acc[nt] = __builtin_amdgcn_mfma_f32_16x16x32_bf16(aa, bfr, acc[nt], 0, 0, 0);
        }
    }
    #pragma unroll
    for (int nt = 0; nt < 4; ++nt)
        #pragma unroll
        for (int r = 0; r < 4; ++r) {
            int c = c0 + w * 16 + lg * 4 + r;
            int n = n0 + nt * 16 + lr;
            size_t idx = ((size_t)b * CC + c) * NPIX + n;
            out[idx] = acc[nt][r] + bp[c] + x[idx];
        }
}

// ---------------------------------------------------------------- launch
extern "C" void kernel_launch(void* const* d_in, const int* in_sizes, int n_in,
                              void* d_out, int out_size, void* d_ws, size_t ws_size,
                              hipStream_t stream) {
    const float* x      = (const float*)d_in[0];
    const float* gamma  = (const float*)d_in[1];
    const float* beta   = (const float*)d_in[2];
    const float* w_qkv  = (const float*)d_in[3];
    const float* b_qkv  = (const float*)d_in[4];
    const float* w_proj = (const float*)d_in[5];
    const float* b_proj = (const float*)d_in[6];
    float* out = (float*)d_out;

    char* ws = (char*)d_ws;
    __hip_bfloat16* qfb  = (__hip_bfloat16*)(ws);                            // 4 MB
    __hip_bfloat16* kfb  = (__hip_bfloat16*)(ws + (4  << 20));               // 4 MB
    __hip_bfloat16* vfb  = (__hip_bfloat16*)(ws + (8  << 20));               // 4 MB
    __hip_bfloat16* obuf = (__hip_bfloat16*)(ws + (12 << 20));               // 4 MB  [8192][256]
    __hip_bfloat16* wqf  = (__hip_bfloat16*)(ws + (16 << 20));               // 384 KB frag
    __hip_bfloat16* wpf  = (__hip_bfloat16*)(ws + (16 << 20) + (512 << 10)); // 128 KB frag

    w_prep<<<128, 256, 0, stream>>>(w_qkv, w_proj, wqf, wpf);
    ln_qkv<<<BB * NPIX / 32, 512, 0, stream>>>(x, gamma, beta, wqf, b_qkv, qfb, kfb, vfb);
    attn_fused7<<<dim3(64, 8), 1024, 0, stream>>>(qfb, kfb, vfb, obuf);
    gemm_proj_res<<<dim3(CC / 64, NPIX / 64, BB), 256, 0, stream>>>(obuf, wpf, b_proj, x, out);
}

// Round 11
// 54.580 us; speedup vs baseline: 1.8912x; 1.0566x over previous
//
#include <hip/hip_runtime.h>
#include <hip/hip_bf16.h>

// Problem constants (B,C,H,W)=(8,256,32,32), heads=8, head_dim=32
#define BB 8
#define CC 256
#define NPIX 1024          // H*W
#define NH 8
#define HD 32
#define QKVO 768           // 3*256
#define EPS 1e-5f

typedef __attribute__((ext_vector_type(4)))  float floatx4;
typedef __attribute__((ext_vector_type(16))) float floatx16;
typedef __attribute__((ext_vector_type(8)))  short bf16x8;

// Q/K/V frag layout (per (bh,tile32) block of 1024 bf16 = [sub2][lane64][elem8]):
//   Q (B-op): lane = (n&31) + 32*((d>>3)&1), sub = d>>4,        elem = d&7
//   K (A-op): lane = (m&31) + 32*((d>>3)&1), sub = d>>4,        elem = d&7
//   V (A-op): lane = d      + 32*((m&15)>>3), sub = (m&31)>>4,  elem = m&7
// Q is pre-scaled by head_dim^-0.5 * log2(e) so softmax is p = 2^st.
//
// Weight frag layout (16x16x32 A/B operand):
//   wf[((tile*8 + kks)*64 + lane)*8 + j] = W[tile*16 + (lane&15)][kks*32 + (lane>>4)*8 + j]
// obuf frag layout (proj B-operand):
//   obf[(((b*64 + nt16)*8 + kks)*64 + lane)*8 + j] = O[b][n = nt16*16 + (lane&15)]
//                                                     [c = kks*32 + (lane>>4)*8 + j]
//   (head h's 32 channels ARE k-slice kks=h, so attn writes its own slice only)

// ---------------------------------------------------------------- weight prep: f32 row-major -> bf16 frag order
__global__ __launch_bounds__(256) void w_prep(const float* __restrict__ wq,
                                              const float* __restrict__ wp,
                                              __hip_bfloat16* __restrict__ wqf,
                                              __hip_bfloat16* __restrict__ wpf) {
    int idx = blockIdx.x * 256 + threadIdx.x;          // 0..32767
    const float* src;
    __hip_bfloat16* dst;
    int n;
    if (idx < 24576) { src = wq; dst = wqf; n = idx; }           // 48*8*64
    else             { src = wp; dst = wpf; n = idx - 24576; }   // 16*8*64
    const int lane = n & 63, kks = (n >> 6) & 7, tile = n >> 9;
    const int row = tile * 16 + (lane & 15);
    const int col = kks * 32 + (lane >> 4) * 8;
    const float* s = src + (size_t)row * CC + col;
    union { bf16x8 v; __hip_bfloat16 h[8]; } pk;
    #pragma unroll
    for (int j = 0; j < 8; ++j) pk.h[j] = __float2bfloat16(s[j]);
    *(bf16x8*)(dst + (size_t)n * 8) = pk.v;
}

// ---------------------------------------------------------------- fused LN + QKV GEMM -> fragment buffers
__global__ __launch_bounds__(512) void ln_qkv(const float* __restrict__ x,
                                              const float* __restrict__ gamma,
                                              const float* __restrict__ beta,
                                              const __hip_bfloat16* __restrict__ wqf,
                                              const float* __restrict__ bq,
                                              __hip_bfloat16* __restrict__ qf,
                                              __hip_bfloat16* __restrict__ kf,
                                              __hip_bfloat16* __restrict__ vf) {
    __shared__ short xbn[32 * 256];      // 16 KB normalized tile, swizzled
    __shared__ float s_part[16][33];
    __shared__ float q_part[16][33];
    __shared__ float s_mu[32], s_rs[32];

    const int tid  = threadIdx.x;
    const int P0   = blockIdx.x * 32;    // global pixel base (32 | 1024: no batch straddle)
    const int b    = P0 >> 10;
    const int nloc = tid & 31;
    const int g    = tid >> 5;           // 0..15
    const float* xb = x + (size_t)b * CC * NPIX + (P0 & 1023);

    // ---- Phase A: stats; load exactly the 16 channels phase B will emit
    float vals[16];
    float s = 0.f, s2 = 0.f;
    #pragma unroll
    for (int j = 0; j < 8; ++j) {
        float v = xb[(size_t)(g * 8 + j) * NPIX + nloc];
        vals[j] = v; s += v; s2 += v * v;
    }
    #pragma unroll
    for (int j = 0; j < 8; ++j) {
        float v = xb[(size_t)(128 + g * 8 + j) * NPIX + nloc];
        vals[8 + j] = v; s += v; s2 += v * v;
    }
    s_part[g][nloc] = s; q_part[g][nloc] = s2;
    __syncthreads();
    if (tid < 32) {
        float ss = 0.f, qq = 0.f;
        #pragma unroll
        for (int k = 0; k < 16; ++k) { ss += s_part[k][tid]; qq += q_part[k][tid]; }
        float mu  = ss * (1.f / CC);
        float var = qq * (1.f / CC) - mu * mu;
        s_mu[tid] = mu; s_rs[tid] = rsqrtf(var + EPS);
    }
    __syncthreads();

    // ---- Phase B: normalize from registers -> swizzled LDS bf16
    {
        const float mu = s_mu[nloc], rs = s_rs[nloc];
        #pragma unroll
        for (int half = 0; half < 2; ++half) {
            int cb = g + half * 16;            // 8-channel block index
            union { bf16x8 v; unsigned short us[8]; } pk;
            #pragma unroll
            for (int j = 0; j < 8; ++j) {
                int c = cb * 8 + j;
                float v = vals[half * 8 + j];
                pk.us[j] = __bfloat16_as_ushort(__float2bfloat16((v - mu) * rs * gamma[c] + beta[c]));
            }
            int idx = (nloc * 256 + cb * 8) ^ ((nloc & 31) << 3);
            *(bf16x8*)(&xbn[idx]) = pk.v;
        }
    }
    __syncthreads();

    // ---- Phase C: GEMM 32 x 768 x 256, weights from frag buffer (contiguous)
    const int w = tid >> 6, lane = tid & 63, lr = lane & 15, lg = lane >> 4;
    const int mstrip = (w & 1) * 16;        // two 16-row strips
    const int otb    = (w >> 1) * 12;       // o-tile base (12 tiles = 192 outputs)
    floatx4 acc[12] = {};
    for (int kks = 0; kks < 8; ++kks) {
        const int arow = mstrip + lr;
        const int aidx = (arow * 256 + kks * 32 + lg * 8) ^ ((arow & 31) << 3);
        bf16x8 a = *(const bf16x8*)(&xbn[aidx]);
        #pragma unroll
        for (int nt = 0; nt < 12; ++nt) {
            bf16x8 bfr = *(const bf16x8*)(wqf + (((size_t)(otb + nt) * 8 + kks) * 64 + lane) * 8);
            acc[nt] = __builtin_amdgcn_mfma_f32_16x16x32_bf16(a, bfr, acc[nt], 0, 0, 0);
        }
    }
    // ---- epilogue: write fragment-order Q/K/V.  Q pre-scaled by scale*log2e.
    const float QSCALE = 0.25503495f;       // 0.17677669529663689 * 1.4426950408889634
    const int m_base = mstrip + lg * 4;     // m_in base (0..28, mult of 4)
    const int tile   = blockIdx.x & 31;     // pixel tile within image
    #pragma unroll
    for (int nt = 0; nt < 12; ++nt) {
        const int o = (otb + nt) * 16 + lr;
        const int h = o / 96, om = o % 96;  // uniform per nt across the 16-lane run
        const float bias = bq[o];
        const size_t fb = (size_t)((b * NH + h) * 32 + tile) * 1024;
        if (om < 64) {                      // Q or K: 4 scalar 2B stores (lane varies with m)
            const int d = om & 31;
            const bool isq = (om < 32);
            __hip_bfloat16* dst = (isq ? qf : kf);
            const float sc = isq ? QSCALE : 1.0f;
            const int off = (d >> 4) * 512 + ((d >> 3) & 1) * 256 + (d & 7);
            #pragma unroll
            for (int r = 0; r < 4; ++r)
                dst[fb + off + (m_base + r) * 8] = __float2bfloat16((acc[nt][r] + bias) * sc);
        } else {                            // V: 4 consecutive m -> one uint2 store
            const int d = om - 64;
            const int half = m_base >> 4, hi = (m_base >> 3) & 1, j0 = m_base & 7;
            union { unsigned short us[4]; uint2 u; } pv;
            #pragma unroll
            for (int r = 0; r < 4; ++r)
                pv.us[r] = __bfloat16_as_ushort(__float2bfloat16(acc[nt][r] + bias));
            *(uint2*)(vf + fb + half * 512 + (d + 32 * hi) * 8 + j0) = pv.u;
        }
    }
}

// ---------------------------------------------------------------- attention v8
// = attn_fused7, but the epilogue writes obuf in proj-B-FRAG order (head h's
// 32 channels are exactly k-slice kks=h), so proj reads contiguously.
__global__ __launch_bounds__(1024, 8) void attn_fused8(const __hip_bfloat16* __restrict__ qf,
                                                       const __hip_bfloat16* __restrict__ kf,
                                                       const __hip_bfloat16* __restrict__ vf,
                                                       __hip_bfloat16* __restrict__ obf) {
    __shared__ float smem_f[3 * 4 * 64 * 17];          // 52224 B, aliased phases
    float (*m_lds)[4][64][17] = (float (*)[4][64][17]) smem_f;  // [3][4][64][17]
    float (*t_lds)[32][33]    = (float (*)[32][33])    smem_f;  // [4][32][33]

    const int flat = blockIdx.y * 64 + blockIdx.x;          // 0..511
    const int bh   = (flat & 7) * 8 + ((flat >> 3) & 7);    // XCD-bijective remap
    const int qg   = flat >> 6;                             // 0..7
    const int b = bh >> 3, h = bh & 7;
    const int tid = threadIdx.x, w = tid >> 6, lane = tid & 63;
    const int lc = lane & 31, hi = lane >> 5;
    const int kq = w >> 2;                         // KV quarter (0..3)
    const int qt = w & 3;                          // q-tile within group
    const int n_tile = qg * 4 + qt;                // q-tile (0..31)

    const __hip_bfloat16* qb = qf + (size_t)(bh * 32 + n_tile) * 1024;
    bf16x8 q0 = *(const bf16x8*)(qb + lane * 8);
    bf16x8 q1 = *(const bf16x8*)(qb + 512 + lane * 8);

    const __hip_bfloat16* kb = kf + (size_t)(bh * 32 + kq * 8) * 1024 + lane * 8;
    const __hip_bfloat16* vb = vf + (size_t)(bh * 32 + kq * 8) * 1024 + lane * 8;

    floatx16 oacc = {0.f,0.f,0.f,0.f,0.f,0.f,0.f,0.f,0.f,0.f,0.f,0.f,0.f,0.f,0.f,0.f};
    float ls0 = 0.f, ls1 = 0.f, ls2 = 0.f, ls3 = 0.f;

    #pragma unroll 2
    for (int t = 0; t < 8; ++t) {
        bf16x8 k0 = *(const bf16x8*)(kb + t * 1024);
        bf16x8 k1 = *(const bf16x8*)(kb + t * 1024 + 512);
        bf16x8 v0 = *(const bf16x8*)(vb + t * 1024);
        bf16x8 v1 = *(const bf16x8*)(vb + t * 1024 + 512);

        floatx16 st = {0.f,0.f,0.f,0.f,0.f,0.f,0.f,0.f,0.f,0.f,0.f,0.f,0.f,0.f,0.f,0.f};
        __builtin_amdgcn_s_setprio(1);
        st = __builtin_amdgcn_mfma_f32_32x32x16_bf16(k0, q0, st, 0, 0, 0);
        st = __builtin_amdgcn_mfma_f32_32x32x16_bf16(k1, q1, st, 0, 0, 0);
        __builtin_amdgcn_s_setprio(0);
        float p[16];
        #pragma unroll
        for (int r = 0; r < 16; ++r) p[r] = __builtin_amdgcn_exp2f(st[r]);   // raw v_exp_f32
        ls0 += p[0] + p[4] + p[8]  + p[12];
        ls1 += p[1] + p[5] + p[9]  + p[13];
        ls2 += p[2] + p[6] + p[10] + p[14];
        ls3 += p[3] + p[7] + p[11] + p[15];
        unsigned int wpk[8];
        #pragma unroll
        for (int k2 = 0; k2 < 8; ++k2)
            asm("v_cvt_pk_bf16_f32 %0, %1, %2" : "=v"(wpk[k2]) : "v"(p[2*k2]), "v"(p[2*k2+1]));
        asm("v_permlane32_swap_b32 %0, %1" : "+v"(wpk[0]), "+v"(wpk[2]));
        asm("v_permlane32_swap_b32 %0, %1" : "+v"(wpk[1]), "+v"(wpk[3]));
        asm("v_permlane32_swap_b32 %0, %1" : "+v"(wpk[4]), "+v"(wpk[6]));
        asm("v_permlane32_swap_b32 %0, %1" : "+v"(wpk[5]), "+v"(wpk[7]));
        union { bf16x8 v; unsigned int u[4]; } pb0, pb1;
        pb0.u[0] = wpk[0]; pb0.u[1] = wpk[1]; pb0.u[2] = wpk[2]; pb0.u[3] = wpk[3];
        pb1.u[0] = wpk[4]; pb1.u[1] = wpk[5]; pb1.u[2] = wpk[6]; pb1.u[3] = wpk[7];
        __builtin_amdgcn_s_setprio(1);
        oacc = __builtin_amdgcn_mfma_f32_32x32x16_bf16(v0, pb0.v, oacc, 0, 0, 0);
        oacc = __builtin_amdgcn_mfma_f32_32x32x16_bf16(v1, pb1.v, oacc, 0, 0, 0);
        __builtin_amdgcn_s_setprio(0);
    }
    float lsum = (ls0 + ls1) + (ls2 + ls3);

    // ---- 4-way KV merge (pure sums -- no max state)
    if (kq > 0) {
        #pragma unroll
        for (int r = 0; r < 16; ++r) m_lds[kq - 1][qt][lane][r] = oacc[r];
        m_lds[kq - 1][qt][lane][16] = lsum;
    }
    __syncthreads();
    float inv = 0.f;
    if (kq == 0) {
        #pragma unroll
        for (int s = 0; s < 3; ++s) {
            #pragma unroll
            for (int r = 0; r < 16; ++r) oacc[r] += m_lds[s][qt][lane][r];
            lsum += m_lds[s][qt][lane][16];
        }
        lsum += __shfl_xor(lsum, 32);
        inv = 1.0f / lsum;
    }
    __syncthreads();          // all m_lds reads done; smem re-used as t_lds
    if (kq == 0) {
        #pragma unroll
        for (int r = 0; r < 16; ++r) {
            int d = (r & 3) + 8 * (r >> 2) + 4 * hi;
            t_lds[qt][lc][d] = oacc[r] * inv;
        }
    }
    __syncthreads();
    if (kq == 0) {
        // frag-order write: block (b, nt16 = n_tile*2+half, kks = h);
        // lane = (n&15) + 16*(d>>3), elem j = d&7  -> one uint4 per half
        const int q = lane >> 4, nl = lane & 15;
        #pragma unroll
        for (int half = 0; half < 2; ++half) {
            union { __hip_bfloat16 h16[8]; uint4 u4; } ov;
            #pragma unroll
            for (int j = 0; j < 8; ++j)
                ov.h16[j] = __float2bfloat16(t_lds[qt][half * 16 + nl][q * 8 + j]);
            *(uint4*)(obf + (((size_t)(b * 64 + n_tile * 2 + half) * 8 + h) * 64 + lane) * 8) = ov.u4;
        }
    }
}

// ---------------------------------------------------------------- proj + residual (both operands frag-order)
__global__ __launch_bounds__(256) void gemm_proj_res(const __hip_bfloat16* __restrict__ obf,
                                                     const __hip_bfloat16* __restrict__ wpf,
                                                     const float* __restrict__ bp,
                                                     const float* __restrict__ x,
                                                     float* __restrict__ out) {
    const int c0 = blockIdx.x * 64, n0 = blockIdx.y * 64, b = blockIdx.z;
    const int tid = threadIdx.x, w = tid >> 6, lane = tid & 63;
    const int lr = lane & 15, lg = lane >> 4;
    const int ct = (c0 >> 4) + w;           // this wave's c-tile (16 rows)
    const int nt16 = n0 >> 4;               // base 16-pixel tile

    floatx4 acc[4] = {};
    for (int kks = 0; kks < 8; ++kks) {
        bf16x8 aa = *(const bf16x8*)(wpf + (((size_t)ct * 8 + kks) * 64 + lane) * 8);
        #pragma unroll
        for (int nt = 0; nt < 4; ++nt) {
            bf16x8 bfr = *(const bf16x8*)(obf + (((size_t)(b * 64 + nt16 + nt) * 8 + kks) * 64 + lane) * 8);
            acc[nt] = __builtin_amdgcn_mfma_f32_16x16x32_bf16(aa, bfr, acc[nt], 0, 0, 0);
        }
    }
    #pragma unroll
    for (int nt = 0; nt < 4; ++nt)
        #pragma unroll
        for (int r = 0; r < 4; ++r) {
            int c = c0 + w * 16 + lg * 4 + r;
            int n = n0 + nt * 16 + lr;
            size_t idx = ((size_t)b * CC + c) * NPIX + n;
            out[idx] = acc[nt][r] + bp[c] + x[idx];
        }
}

// ---------------------------------------------------------------- launch
extern "C" void kernel_launch(void* const* d_in, const int* in_sizes, int n_in,
                              void* d_out, int out_size, void* d_ws, size_t ws_size,
                              hipStream_t stream) {
    const float* x      = (const float*)d_in[0];
    const float* gamma  = (const float*)d_in[1];
    const float* beta   = (const float*)d_in[2];
    const float* w_qkv  = (const float*)d_in[3];
    const float* b_qkv  = (const float*)d_in[4];
    const float* w_proj = (const float*)d_in[5];
    const float* b_proj = (const float*)d_in[6];
    float* out = (float*)d_out;

    char* ws = (char*)d_ws;
    __hip_bfloat16* qfb  = (__hip_bfloat16*)(ws);                            // 4 MB
    __hip_bfloat16* kfb  = (__hip_bfloat16*)(ws + (4  << 20));               // 4 MB
    __hip_bfloat16* vfb  = (__hip_bfloat16*)(ws + (8  << 20));               // 4 MB
    __hip_bfloat16* obf  = (__hip_bfloat16*)(ws + (12 << 20));               // 4 MB frag-order
    __hip_bfloat16* wqf  = (__hip_bfloat16*)(ws + (16 << 20));               // 384 KB frag
    __hip_bfloat16* wpf  = (__hip_bfloat16*)(ws + (16 << 20) + (512 << 10)); // 128 KB frag

    w_prep<<<128, 256, 0, stream>>>(w_qkv, w_proj, wqf, wpf);
    ln_qkv<<<BB * NPIX / 32, 512, 0, stream>>>(x, gamma, beta, wqf, b_qkv, qfb, kfb, vfb);
    attn_fused8<<<dim3(64, 8), 1024, 0, stream>>>(qfb, kfb, vfb, obf);
    gemm_proj_res<<<dim3(CC / 64, NPIX / 64, BB), 256, 0, stream>>>(obf, wpf, b_proj, x, out);
}

// Round 13
// 48.991 us; speedup vs baseline: 2.1069x; 1.1141x over previous
//
#include <hip/hip_runtime.h>
#include <hip/hip_bf16.h>

// Problem constants (B,C,H,W)=(8,256,32,32), heads=8, head_dim=32
#define BB 8
#define CC 256
#define NPIX 1024          // H*W
#define NH 8
#define HD 32
#define QKVO 768           // 3*256
#define EPS 1e-5f

typedef __attribute__((ext_vector_type(4)))  float floatx4;
typedef __attribute__((ext_vector_type(16))) float floatx16;
typedef __attribute__((ext_vector_type(8)))  short bf16x8;

// Q/K/V frag layout (per (bh,tile32) block of 1024 bf16 = [sub2][lane64][elem8]):
//   Q (B-op): lane = (n&31) + 32*((d>>3)&1), sub = d>>4,        elem = d&7
//   K (A-op): lane = (m&31) + 32*((d>>3)&1), sub = d>>4,        elem = d&7
//   V (A-op): lane = d      + 32*((m&15)>>3), sub = (m&31)>>4,  elem = m&7
// Q pre-scaled by head_dim^-0.5 * log2(e) so softmax is p = 2^st.
// Weight frags: wf[((tile*8+kks)*64+lane)*8+j] = W[tile*16+(lane&15)][kks*32+(lane>>4)*8+j]
// obuf frags  : obf[(((b*64+nt16)*8+kks)*64+lane)*8+j] = O[b][nt16*16+(lane&15)][kks*32+(lane>>4)*8+j]

// ---------------------------------------------------------------- weight prep: f32 row-major -> bf16 frag order
__global__ __launch_bounds__(256) void w_prep(const float* __restrict__ wq,
                                              const float* __restrict__ wp,
                                              __hip_bfloat16* __restrict__ wqf,
                                              __hip_bfloat16* __restrict__ wpf) {
    int idx = blockIdx.x * 256 + threadIdx.x;          // 0..32767
    const float* src;
    __hip_bfloat16* dst;
    int n;
    if (idx < 24576) { src = wq; dst = wqf; n = idx; }           // 48*8*64
    else             { src = wp; dst = wpf; n = idx - 24576; }   // 16*8*64
    const int lane = n & 63, kks = (n >> 6) & 7, tile = n >> 9;
    const int row = tile * 16 + (lane & 15);
    const int col = kks * 32 + (lane >> 4) * 8;
    const float* s = src + (size_t)row * CC + col;
    union { bf16x8 v; __hip_bfloat16 h[8]; } pk;
    #pragma unroll
    for (int j = 0; j < 8; ++j) pk.h[j] = __float2bfloat16(s[j]);
    *(bf16x8*)(dst + (size_t)n * 8) = pk.v;
}

// ---------------------------------------------------------------- fused LN + QKV GEMM -> fragment buffers
// v2: 16-pixel tile per block -> grid 512 (2 blocks/CU, 16 waves/CU vs 8).
// 512 threads = 8 waves; each wave computes 6 o-tiles (96 outputs) for the
// single 16-row A-tile.
__global__ __launch_bounds__(512) void ln_qkv(const float* __restrict__ x,
                                              const float* __restrict__ gamma,
                                              const float* __restrict__ beta,
                                              const __hip_bfloat16* __restrict__ wqf,
                                              const float* __restrict__ bq,
                                              __hip_bfloat16* __restrict__ qf,
                                              __hip_bfloat16* __restrict__ kf,
                                              __hip_bfloat16* __restrict__ vf) {
    __shared__ short xbn[16 * 256];      // 8 KB normalized tile, swizzled
    __shared__ float s_part[32][17];
    __shared__ float q_part[32][17];
    __shared__ float s_mu[16], s_rs[16];

    const int tid  = threadIdx.x;
    const int P0   = blockIdx.x * 16;    // global pixel base (16 | 1024)
    const int b    = P0 >> 10;
    const int nloc = tid & 15;           // pixel within tile
    const int g    = tid >> 4;           // 0..31 channel group (8 ch each)
    const float* xb = x + (size_t)b * CC * NPIX + (P0 & 1023);

    // ---- Phase A: stats; each thread loads its 8 channels, keeps them
    float vals[8];
    float s = 0.f, s2 = 0.f;
    #pragma unroll
    for (int j = 0; j < 8; ++j) {
        float v = xb[(size_t)(g * 8 + j) * NPIX + nloc];
        vals[j] = v; s += v; s2 += v * v;
    }
    s_part[g][nloc] = s; q_part[g][nloc] = s2;
    __syncthreads();
    if (tid < 16) {
        float ss = 0.f, qq = 0.f;
        #pragma unroll
        for (int k = 0; k < 32; ++k) { ss += s_part[k][tid]; qq += q_part[k][tid]; }
        float mu  = ss * (1.f / CC);
        float var = qq * (1.f / CC) - mu * mu;
        s_mu[tid] = mu; s_rs[tid] = rsqrtf(var + EPS);
    }
    __syncthreads();

    // ---- Phase B: normalize from registers -> swizzled LDS bf16 (one 16B store)
    {
        const float mu = s_mu[nloc], rs = s_rs[nloc];
        union { bf16x8 v; unsigned short us[8]; } pk;
        #pragma unroll
        for (int j = 0; j < 8; ++j) {
            int c = g * 8 + j;
            pk.us[j] = __bfloat16_as_ushort(__float2bfloat16((vals[j] - mu) * rs * gamma[c] + beta[c]));
        }
        int idx = (nloc * 256 + g * 8) ^ (nloc << 3);
        *(bf16x8*)(&xbn[idx]) = pk.v;
    }
    __syncthreads();

    // ---- Phase C: GEMM 16 x 768 x 256, weights from frag buffer (contiguous)
    const int w = tid >> 6, lane = tid & 63, lr = lane & 15, lg = lane >> 4;
    const int otb = w * 6;                  // 6 o-tiles per wave
    floatx4 acc[6] = {};
    for (int kks = 0; kks < 8; ++kks) {
        const int aidx = (lr * 256 + kks * 32 + lg * 8) ^ (lr << 3);
        bf16x8 a = *(const bf16x8*)(&xbn[aidx]);
        #pragma unroll
        for (int nt = 0; nt < 6; ++nt) {
            bf16x8 bfr = *(const bf16x8*)(wqf + (((size_t)(otb + nt) * 8 + kks) * 64 + lane) * 8);
            acc[nt] = __builtin_amdgcn_mfma_f32_16x16x32_bf16(a, bfr, acc[nt], 0, 0, 0);
        }
    }
    // ---- epilogue: write fragment-order Q/K/V.  Q pre-scaled by scale*log2e.
    const float QSCALE = 0.25503495f;       // 0.17677669529663689 * 1.4426950408889634
    const int mb32   = (P0 & 16) + lg * 4;  // m base within the 32-pixel frag tile
    const int tile32 = (P0 & 1023) >> 5;    // 32-pixel tile within image
    #pragma unroll
    for (int nt = 0; nt < 6; ++nt) {
        const int o = (otb + nt) * 16 + lr;
        const int h = o / 96, om = o % 96;  // uniform per nt across the 16-lane run
        const float bias = bq[o];
        const size_t fb = (size_t)((b * NH + h) * 32 + tile32) * 1024;
        if (om < 64) {                      // Q or K: 4 scalar 2B stores
            const int d = om & 31;
            const bool isq = (om < 32);
            __hip_bfloat16* dst = (isq ? qf : kf);
            const float sc = isq ? QSCALE : 1.0f;
            const int off = (d >> 4) * 512 + ((d >> 3) & 1) * 256 + (d & 7);
            #pragma unroll
            for (int r = 0; r < 4; ++r)
                dst[fb + off + (size_t)(mb32 + r) * 8] = __float2bfloat16((acc[nt][r] + bias) * sc);
        } else {                            // V: 4 consecutive m -> one uint2 store
            const int d = om - 64;
            const int half = mb32 >> 4, hi2 = (mb32 >> 3) & 1, j0 = mb32 & 7;
            union { unsigned short us[4]; uint2 u; } pv;
            #pragma unroll
            for (int r = 0; r < 4; ++r)
                pv.us[r] = __bfloat16_as_ushort(__float2bfloat16(acc[nt][r] + bias));
            *(uint2*)(vf + fb + half * 512 + (d + 32 * hi2) * 8 + j0) = pv.u;
        }
    }
}

// ---------------------------------------------------------------- attention v8 (unchanged from R11)
__global__ __launch_bounds__(1024, 8) void attn_fused8(const __hip_bfloat16* __restrict__ qf,
                                                       const __hip_bfloat16* __restrict__ kf,
                                                       const __hip_bfloat16* __restrict__ vf,
                                                       __hip_bfloat16* __restrict__ obf) {
    __shared__ float smem_f[3 * 4 * 64 * 17];          // 52224 B, aliased phases
    float (*m_lds)[4][64][17] = (float (*)[4][64][17]) smem_f;  // [3][4][64][17]
    float (*t_lds)[32][33]    = (float (*)[32][33])    smem_f;  // [4][32][33]

    const int flat = blockIdx.y * 64 + blockIdx.x;          // 0..511
    const int bh   = (flat & 7) * 8 + ((flat >> 3) & 7);    // XCD-bijective remap
    const int qg   = flat >> 6;                             // 0..7
    const int b = bh >> 3, h = bh & 7;
    const int tid = threadIdx.x, w = tid >> 6, lane = tid & 63;
    const int lc = lane & 31, hi = lane >> 5;
    const int kq = w >> 2;                         // KV quarter (0..3)
    const int qt = w & 3;                          // q-tile within group
    const int n_tile = qg * 4 + qt;                // q-tile (0..31)

    const __hip_bfloat16* qb = qf + (size_t)(bh * 32 + n_tile) * 1024;
    bf16x8 q0 = *(const bf16x8*)(qb + lane * 8);
    bf16x8 q1 = *(const bf16x8*)(qb + 512 + lane * 8);

    const __hip_bfloat16* kb = kf + (size_t)(bh * 32 + kq * 8) * 1024 + lane * 8;
    const __hip_bfloat16* vb = vf + (size_t)(bh * 32 + kq * 8) * 1024 + lane * 8;

    floatx16 oacc = {0.f,0.f,0.f,0.f,0.f,0.f,0.f,0.f,0.f,0.f,0.f,0.f,0.f,0.f,0.f,0.f};
    float ls0 = 0.f, ls1 = 0.f, ls2 = 0.f, ls3 = 0.f;

    #pragma unroll 2
    for (int t = 0; t < 8; ++t) {
        bf16x8 k0 = *(const bf16x8*)(kb + t * 1024);
        bf16x8 k1 = *(const bf16x8*)(kb + t * 1024 + 512);
        bf16x8 v0 = *(const bf16x8*)(vb + t * 1024);
        bf16x8 v1 = *(const bf16x8*)(vb + t * 1024 + 512);

        floatx16 st = {0.f,0.f,0.f,0.f,0.f,0.f,0.f,0.f,0.f,0.f,0.f,0.f,0.f,0.f,0.f,0.f};
        __builtin_amdgcn_s_setprio(1);
        st = __builtin_amdgcn_mfma_f32_32x32x16_bf16(k0, q0, st, 0, 0, 0);
        st = __builtin_amdgcn_mfma_f32_32x32x16_bf16(k1, q1, st, 0, 0, 0);
        __builtin_amdgcn_s_setprio(0);
        float p[16];
        #pragma unroll
        for (int r = 0; r < 16; ++r) p[r] = __builtin_amdgcn_exp2f(st[r]);   // raw v_exp_f32
        ls0 += p[0] + p[4] + p[8]  + p[12];
        ls1 += p[1] + p[5] + p[9]  + p[13];
        ls2 += p[2] + p[6] + p[10] + p[14];
        ls3 += p[3] + p[7] + p[11] + p[15];
        unsigned int wpk[8];
        #pragma unroll
        for (int k2 = 0; k2 < 8; ++k2)
            asm("v_cvt_pk_bf16_f32 %0, %1, %2" : "=v"(wpk[k2]) : "v"(p[2*k2]), "v"(p[2*k2+1]));
        asm("v_permlane32_swap_b32 %0, %1" : "+v"(wpk[0]), "+v"(wpk[2]));
        asm("v_permlane32_swap_b32 %0, %1" : "+v"(wpk[1]), "+v"(wpk[3]));
        asm("v_permlane32_swap_b32 %0, %1" : "+v"(wpk[4]), "+v"(wpk[6]));
        asm("v_permlane32_swap_b32 %0, %1" : "+v"(wpk[5]), "+v"(wpk[7]));
        union { bf16x8 v; unsigned int u[4]; } pb0, pb1;
        pb0.u[0] = wpk[0]; pb0.u[1] = wpk[1]; pb0.u[2] = wpk[2]; pb0.u[3] = wpk[3];
        pb1.u[0] = wpk[4]; pb1.u[1] = wpk[5]; pb1.u[2] = wpk[6]; pb1.u[3] = wpk[7];
        __builtin_amdgcn_s_setprio(1);
        oacc = __builtin_amdgcn_mfma_f32_32x32x16_bf16(v0, pb0.v, oacc, 0, 0, 0);
        oacc = __builtin_amdgcn_mfma_f32_32x32x16_bf16(v1, pb1.v, oacc, 0, 0, 0);
        __builtin_amdgcn_s_setprio(0);
    }
    float lsum = (ls0 + ls1) + (ls2 + ls3);

    // ---- 4-way KV merge (pure sums -- no max state)
    if (kq > 0) {
        #pragma unroll
        for (int r = 0; r < 16; ++r) m_lds[kq - 1][qt][lane][r] = oacc[r];
        m_lds[kq - 1][qt][lane][16] = lsum;
    }
    __syncthreads();
    float inv = 0.f;
    if (kq == 0) {
        #pragma unroll
        for (int s = 0; s < 3; ++s) {
            #pragma unroll
            for (int r = 0; r < 16; ++r) oacc[r] += m_lds[s][qt][lane][r];
            lsum += m_lds[s][qt][lane][16];
        }
        lsum += __shfl_xor(lsum, 32);
        inv = 1.0f / lsum;
    }
    __syncthreads();          // all m_lds reads done; smem re-used as t_lds
    if (kq == 0) {
        #pragma unroll
        for (int r = 0; r < 16; ++r) {
            int d = (r & 3) + 8 * (r >> 2) + 4 * hi;
            t_lds[qt][lc][d] = oacc[r] * inv;
        }
    }
    __syncthreads();
    if (kq == 0) {
        // frag-order write: block (b, nt16 = n_tile*2+half, kks = h)
        const int q = lane >> 4, nl = lane & 15;
        #pragma unroll
        for (int half = 0; half < 2; ++half) {
            union { __hip_bfloat16 h16[8]; uint4 u4; } ov;
            #pragma unroll
            for (int j = 0; j < 8; ++j)
                ov.h16[j] = __float2bfloat16(t_lds[qt][half * 16 + nl][q * 8 + j]);
            *(uint4*)(obf + (((size_t)(b * 64 + n_tile * 2 + half) * 8 + h) * 64 + lane) * 8) = ov.u4;
        }
    }
}

// ---------------------------------------------------------------- proj + residual (both operands frag-order)
__global__ __launch_bounds__(256) void gemm_proj_res(const __hip_bfloat16* __restrict__ obf,
                                                     const __hip_bfloat16* __restrict__ wpf,
                                                     const float* __restrict__ bp,
                                                     const float* __restrict__ x,
                                                     float* __restrict__ out) {
    const int c0 = blockIdx.x * 64, n0 = blockIdx.y * 64, b = blockIdx.z;
    const int tid = threadIdx.x, w = tid >> 6, lane = tid & 63;
    const int lr = lane & 15, lg = lane >> 4;
    const int ct = (c0 >> 4) + w;           // this wave's c-tile (16 rows)
    const int nt16 = n0 >> 4;               // base 16-pixel tile

    floatx4 acc[4] = {};
    for (int kks = 0; kks < 8; ++kks) {
        bf16x8 aa = *(const bf16x8*)(wpf + (((size_t)ct * 8 + kks) * 64 + lane) * 8);
        #pragma unroll
        for (int nt = 0; nt < 4; ++nt) {
            bf16x8 bfr = *(const bf16x8*)(obf + (((size_t)(b * 64 + nt16 + nt) * 8 + kks) * 64 + lane) * 8);
            acc[nt] = __builtin_amdgcn_mfma_f32_16x16x32_bf16(aa, bfr, acc[nt], 0, 0, 0);
        }
    }
    #pragma unroll
    for (int nt = 0; nt < 4; ++nt)
        #pragma unroll
        for (int r = 0; r < 4; ++r) {
            int c = c0 + w * 16 + lg * 4 + r;
            int n = n0 + nt * 16 + lr;
            size_t idx = ((size_t)b * CC + c) * NPIX + n;
            out[idx] = acc[nt][r] + bp[c] + x[idx];
        }
}

// ---------------------------------------------------------------- launch
extern "C" void kernel_launch(void* const* d_in, const int* in_sizes, int n_in,
                              void* d_out, int out_size, void* d_ws, size_t ws_size,
                              hipStream_t stream) {
    const float* x      = (const float*)d_in[0];
    const float* gamma  = (const float*)d_in[1];
    const float* beta   = (const float*)d_in[2];
    const float* w_qkv  = (const float*)d_in[3];
    const float* b_qkv  = (const float*)d_in[4];
    const float* w_proj = (const float*)d_in[5];
    const float* b_proj = (const float*)d_in[6];
    float* out = (float*)d_out;

    char* ws = (char*)d_ws;
    __hip_bfloat16* qfb  = (__hip_bfloat16*)(ws);                            // 4 MB
    __hip_bfloat16* kfb  = (__hip_bfloat16*)(ws + (4  << 20));               // 4 MB
    __hip_bfloat16* vfb  = (__hip_bfloat16*)(ws + (8  << 20));               // 4 MB
    __hip_bfloat16* obf  = (__hip_bfloat16*)(ws + (12 << 20));               // 4 MB frag-order
    __hip_bfloat16* wqf  = (__hip_bfloat16*)(ws + (16 << 20));               // 384 KB frag
    __hip_bfloat16* wpf  = (__hip_bfloat16*)(ws + (16 << 20) + (512 << 10)); // 128 KB frag

    w_prep<<<128, 256, 0, stream>>>(w_qkv, w_proj, wqf, wpf);
    ln_qkv<<<BB * NPIX / 16, 512, 0, stream>>>(x, gamma, beta, wqf, b_qkv, qfb, kfb, vfb);
    attn_fused8<<<dim3(64, 8), 1024, 0, stream>>>(qfb, kfb, vfb, obf);
    gemm_proj_res<<<dim3(CC / 64, NPIX / 64, BB), 256, 0, stream>>>(obf, wpf, b_proj, x, out);
}